// Round 2
// baseline (331.335 us; speedup 1.0000x reference)
//
#include <hip/hip_runtime.h>

// ws layout (float offsets)
// W repacked: ws2[part][ggp(8)][k4(512)][jj(10)][c(4)]  -> lane reads 10
// contiguous float4 (640B) per k-step with a single base pointer.
#define WS2X  0
#define WS2G  163840           // 8*512*10*4
#define WSL   327680           // loss column (80)
#define WSC1  (WSL+80)         // folded gate-1 constants (80)
#define WSC2  (WSC1+80)        // folded gate-2 constants (80)
#define WSPF  (WSC2+80)        // poly factor scalar

__device__ __forceinline__ float fsig(float x){ return 1.0f/(1.0f + __expf(-x)); }
__device__ __forceinline__ float ftanh(float x){ float e = __expf(2.0f*x); return 1.0f - 2.0f/(e+1.0f); }

__global__ __launch_bounds__(256,1) void prep_kernel(
    const float* __restrict__ W_ih1, const float* __restrict__ b_ih1,
    const float* __restrict__ W_hh1, const float* __restrict__ b_hh1,
    const float* __restrict__ b_ih2, const float* __restrict__ W_hh2,
    const float* __restrict__ b_hh2, const float* __restrict__ h1_0,
    const float* __restrict__ h2_0, const float* __restrict__ alpha_raw,
    const int* __restrict__ t, float* __restrict__ ws)
{
  const int b = blockIdx.x;            // 160 blocks: gate(80) x part(2)
  const int gate = b >> 1, part = b & 1;
  const float* src = W_ih1 + (size_t)gate*4097 + (part ? 2049 : 0);
  float* dst = ws + (part ? WS2G : WS2X) + (gate/10)*20480 + (gate%10)*4;
  for (int k4 = threadIdx.x; k4 < 512; k4 += 256) {
    float4 v;
    v.x = src[k4*4+0]; v.y = src[k4*4+1]; v.z = src[k4*4+2]; v.w = src[k4*4+3];
    *(float4*)(dst + (size_t)k4*160) = v;
  }
  if (b == 0) {
    const int tix = threadIdx.x;
    if (tix < 80) {
      float s = b_ih1[tix] + b_hh1[tix];
      for (int j = 0; j < 20; ++j) s += W_hh1[tix*20+j]*h1_0[j];
      ws[WSC1+tix] = s;
    } else if (tix < 160) {
      const int kk = tix - 80;
      float s = b_ih2[kk] + b_hh2[kk];
      for (int j = 0; j < 20; ++j) s += W_hh2[kk*20+j]*h2_0[j];
      ws[WSC2+kk] = s;
    } else if (tix < 240) {
      const int kk = tix - 160;
      ws[WSL+kk] = W_ih1[(size_t)kk*4097 + 2048];   // loss column
    } else if (tix == 240) {
      const float tv = (float)(*t);
      float pf = 0.f, term = 1.f;
      for (int j = 0; j < 3; ++j) {
        float a = alpha_raw[j];
        float sp = (a > 20.f) ? a : log1pf(__expf(a));
        pf += sp*term; term *= tv;                   // t^0 == 1 even at t=0
      }
      pf *= powf(0.99f, tv);
      ws[WSPF] = pf;
    }
  }
}

// 512 blocks x 512 threads. Block = 8 rows. 8 waves split K (256 each).
// Lane = 16 gate-groups x 4 row-groups; lane tile = 10 gates x 2 rows.
// No LDS staging: x/grad read direct (8-way broadcast dup, L1/L2 hits).
__global__ __launch_bounds__(512,4) void main_kernel(
    const float* __restrict__ x, const float* __restrict__ loss,
    const float* __restrict__ grad, const float* __restrict__ W_ih2,
    const float* __restrict__ W_out, const float* __restrict__ b_out,
    const float* __restrict__ c1_0, const float* __restrict__ c2_0,
    const float* __restrict__ ws, float* __restrict__ out)
{
  __shared__ float pbuf[8*8*161];      // partial[w][row][pg], pad 161 vs bank hits
  __shared__ float wih2[1600];
  __shared__ float g1[8][80];
  __shared__ float h1s[8][20], h2s[8][20];
  __shared__ float c10[20], c20[20];
  __shared__ float invX[8], invG[8], lscA[8], axv[8];
  __shared__ unsigned smaxX[8], smaxG[8];

  const int tid  = threadIdx.x;
  const int w    = tid >> 6, lane = tid & 63;
  const int gg   = lane >> 2, rg = lane & 3;
  const int part = gg >> 3;            // 0 = x part, 1 = grad part
  const int ggp  = gg & 7;
  const int r0   = blockIdx.x * 8;

  for (int i = tid; i < 1600; i += 512) wih2[i] = W_ih2[i];
  if (tid < 20) { c10[tid] = c1_0[tid]; c20[tid] = c2_0[tid]; }
  if (tid < 8)  { smaxX[tid] = 0u; smaxG[tid] = 0u; }
  __syncthreads();

  const float* xsrc = part ? grad : x;
  const float* p0 = xsrc + (size_t)(r0 + 2*rg)*2048 + w*256;
  const float* p1 = p0 + 2048;
  const float* pw = ws + (part ? WS2G : WS2X) + (size_t)ggp*20480 + (size_t)(w*64)*160;

  float acc[10][2];
  #pragma unroll
  for (int jj = 0; jj < 10; ++jj) { acc[jj][0] = 0.f; acc[jj][1] = 0.f; }
  float vm0 = 0.f, vm1 = 0.f;

  #pragma unroll 1
  for (int kk = 0; kk < 64; ++kk) {
    const float4 xa = *(const float4*)p0;
    const float4 xb = *(const float4*)p1;
    float4 wv[10];
    #pragma unroll
    for (int jj = 0; jj < 10; ++jj) wv[jj] = *(const float4*)(pw + jj*4);
    #pragma unroll
    for (int jj = 0; jj < 10; ++jj) {
      acc[jj][0] = fmaf(wv[jj].x, xa.x, acc[jj][0]);
      acc[jj][0] = fmaf(wv[jj].y, xa.y, acc[jj][0]);
      acc[jj][0] = fmaf(wv[jj].z, xa.z, acc[jj][0]);
      acc[jj][0] = fmaf(wv[jj].w, xa.w, acc[jj][0]);
      acc[jj][1] = fmaf(wv[jj].x, xb.x, acc[jj][1]);
      acc[jj][1] = fmaf(wv[jj].y, xb.y, acc[jj][1]);
      acc[jj][1] = fmaf(wv[jj].z, xb.z, acc[jj][1]);
      acc[jj][1] = fmaf(wv[jj].w, xb.w, acc[jj][1]);
    }
    vm0 = fmaxf(vm0, fmaxf(fmaxf(fabsf(xa.x),fabsf(xa.y)), fmaxf(fabsf(xa.z),fabsf(xa.w))));
    vm1 = fmaxf(vm1, fmaxf(fmaxf(fabsf(xb.x),fabsf(xb.y)), fmaxf(fabsf(xb.z),fabsf(xb.w))));
    p0 += 4; p1 += 4; pw += 160;
  }

  if (ggp == 0) {                      // one lane per (part,row-pair) per wave
    unsigned* dm = part ? smaxG : smaxX;
    atomicMax(&dm[2*rg],   __float_as_uint(vm0));
    atomicMax(&dm[2*rg+1], __float_as_uint(vm1));
  }
  #pragma unroll
  for (int jj = 0; jj < 10; ++jj) {    // pg = gg*10+jj: 0..79 x-part, 80..159 g-part
    pbuf[(w*8 + 2*rg+0)*161 + gg*10+jj] = acc[jj][0];
    pbuf[(w*8 + 2*rg+1)*161 + gg*10+jj] = acc[jj][1];
  }
  __syncthreads();

  if (tid < 8) {
    float ax = __uint_as_float(smaxX[tid]); ax = (ax > 0.f) ? ax : 1.0f;
    axv[tid] = ax; invX[tid] = 1.0f/ax;
    float ag = __uint_as_float(smaxG[tid]); ag = (ag > 0.f) ? ag : 1.0f;
    invG[tid] = 1.0f/ag;
    float l  = loss[r0 + tid];
    float al = fabsf(l); al = (al > 0.f) ? al : 1.0f;
    lscA[tid] = l / al;
  }
  __syncthreads();

  for (int idx = tid; idx < 640; idx += 512) {       // gates 1
    const int r = idx / 80, k2 = idx - r*80;
    float sx = 0.f, sg = 0.f;
    #pragma unroll
    for (int ww = 0; ww < 8; ++ww) {
      sx += pbuf[(ww*8 + r)*161 + k2];
      sg += pbuf[(ww*8 + r)*161 + 80 + k2];
    }
    g1[r][k2] = sx*invX[r] + sg*invG[r] + ws[WSL+k2]*lscA[r] + ws[WSC1+k2];
  }
  __syncthreads();

  if (tid < 160) {                                   // cell 1
    const int r = tid / 20, j = tid - r*20;
    const float gi = g1[r][j], gf = g1[r][20+j], gc = g1[r][40+j], go = g1[r][60+j];
    const float c1 = fsig(gf)*c10[j] + fsig(gi)*ftanh(gc);
    h1s[r][j] = fsig(go)*ftanh(c1);
  }
  __syncthreads();

  for (int idx = tid; idx < 640; idx += 512) {       // gates 2
    const int r = idx / 80, k2 = idx - r*80;
    float s = ws[WSC2+k2];
    #pragma unroll
    for (int j = 0; j < 20; ++j) s += wih2[k2*20+j]*h1s[r][j];
    g1[r][k2] = s;
  }
  __syncthreads();

  if (tid < 160) {                                   // cell 2
    const int r = tid / 20, j = tid - r*20;
    const float gi = g1[r][j], gf = g1[r][20+j], gc = g1[r][40+j], go = g1[r][60+j];
    const float c2v = fsig(gf)*c20[j] + fsig(gi)*ftanh(gc);
    h2s[r][j] = fsig(go)*ftanh(c2v);
  }
  __syncthreads();

  const float pf = ws[WSPF];                         // output GEMV + tanh + scale
  #pragma unroll
  for (int q = 0; q < 4; ++q) {
    const int d = q*512 + tid;
    const float4* wr = (const float4*)(W_out + (size_t)d*20);
    const float4 w0 = wr[0], w1 = wr[1], w2 = wr[2], w3 = wr[3], w4 = wr[4];
    const float bo = b_out[d];
    #pragma unroll
    for (int r = 0; r < 8; ++r) {
      const float4* hp = (const float4*)&h2s[r][0];
      const float4 h0 = hp[0], h1v = hp[1], h2v = hp[2], h3v = hp[3], h4v = hp[4];
      float v = bo;
      v += w0.x*h0.x  + w0.y*h0.y  + w0.z*h0.z  + w0.w*h0.w;
      v += w1.x*h1v.x + w1.y*h1v.y + w1.z*h1v.z + w1.w*h1v.w;
      v += w2.x*h2v.x + w2.y*h2v.y + w2.z*h2v.z + w2.w*h2v.w;
      v += w3.x*h3v.x + w3.y*h3v.y + w3.z*h3v.z + w3.w*h3v.w;
      v += w4.x*h4v.x + w4.y*h4v.y + w4.z*h4v.z + w4.w*h4v.w;
      out[(size_t)(r0+r)*2048 + d] = pf * axv[r] * ftanh(v);
    }
  }
}

extern "C" void kernel_launch(void* const* d_in, const int* in_sizes, int n_in,
                              void* d_out, int out_size, void* d_ws, size_t ws_size,
                              hipStream_t stream)
{
  const float* x      = (const float*)d_in[0];
  const float* loss   = (const float*)d_in[1];
  const float* grad   = (const float*)d_in[2];
  const float* W_ih1  = (const float*)d_in[3];
  const float* b_ih1  = (const float*)d_in[4];
  const float* W_hh1  = (const float*)d_in[5];
  const float* b_hh1  = (const float*)d_in[6];
  const float* W_ih2  = (const float*)d_in[7];
  const float* b_ih2  = (const float*)d_in[8];
  const float* W_hh2  = (const float*)d_in[9];
  const float* b_hh2  = (const float*)d_in[10];
  const float* W_out  = (const float*)d_in[11];
  const float* b_out  = (const float*)d_in[12];
  const float* h1_0   = (const float*)d_in[13];
  const float* c1_0   = (const float*)d_in[14];
  const float* h2_0   = (const float*)d_in[15];
  const float* c2_0   = (const float*)d_in[16];
  const float* alpha  = (const float*)d_in[17];
  const int*   t      = (const int*)d_in[18];
  float* ws  = (float*)d_ws;
  float* out = (float*)d_out;

  hipLaunchKernelGGL(prep_kernel, dim3(160), dim3(256), 0, stream,
                     W_ih1, b_ih1, W_hh1, b_hh1, b_ih2, W_hh2, b_hh2,
                     h1_0, h2_0, alpha, t, ws);
  hipLaunchKernelGGL(main_kernel, dim3(512), dim3(512), 0, stream,
                     x, loss, grad, W_ih2, W_out, b_out, c1_0, c2_0, ws, out);
}

// Round 3
// 227.003 us; speedup vs baseline: 1.4596x; 1.4596x over previous
//
#include <hip/hip_runtime.h>

// ws layout (float offsets)
// W repacked: ws2[part][ggp(8)][k4(512)][jj(10)][c(4)]  -> lane reads 10
// contiguous float4 (640B) per k-step with a single base pointer.
#define WS2X  0
#define WS2G  163840           // 8*512*10*4
#define WSL   327680           // loss column (80)
#define WSC1  (WSL+80)         // folded gate-1 constants (80)
#define WSC2  (WSC1+80)        // folded gate-2 constants (80)
#define WSPF  (WSC2+80)        // poly factor scalar

__device__ __forceinline__ float fsig(float x){ return 1.0f/(1.0f + __expf(-x)); }
__device__ __forceinline__ float ftanh(float x){ float e = __expf(2.0f*x); return 1.0f - 2.0f/(e+1.0f); }

__global__ __launch_bounds__(256,1) void prep_kernel(
    const float* __restrict__ W_ih1, const float* __restrict__ b_ih1,
    const float* __restrict__ W_hh1, const float* __restrict__ b_hh1,
    const float* __restrict__ b_ih2, const float* __restrict__ W_hh2,
    const float* __restrict__ b_hh2, const float* __restrict__ h1_0,
    const float* __restrict__ h2_0, const float* __restrict__ alpha_raw,
    const int* __restrict__ t, float* __restrict__ ws)
{
  const int b = blockIdx.x;            // 160 blocks: gate(80) x part(2)
  const int gate = b >> 1, part = b & 1;
  const float* src = W_ih1 + (size_t)gate*4097 + (part ? 2049 : 0);
  float* dst = ws + (part ? WS2G : WS2X) + (gate/10)*20480 + (gate%10)*4;
  for (int k4 = threadIdx.x; k4 < 512; k4 += 256) {
    float4 v;
    v.x = src[k4*4+0]; v.y = src[k4*4+1]; v.z = src[k4*4+2]; v.w = src[k4*4+3];
    *(float4*)(dst + (size_t)k4*160) = v;
  }
  if (b == 0) {
    const int tix = threadIdx.x;
    if (tix < 80) {
      float s = b_ih1[tix] + b_hh1[tix];
      for (int j = 0; j < 20; ++j) s += W_hh1[tix*20+j]*h1_0[j];
      ws[WSC1+tix] = s;
    } else if (tix < 160) {
      const int kk = tix - 80;
      float s = b_ih2[kk] + b_hh2[kk];
      for (int j = 0; j < 20; ++j) s += W_hh2[kk*20+j]*h2_0[j];
      ws[WSC2+kk] = s;
    } else if (tix < 240) {
      const int kk = tix - 160;
      ws[WSL+kk] = W_ih1[(size_t)kk*4097 + 2048];   // loss column
    } else if (tix == 240) {
      const float tv = (float)(*t);
      float pf = 0.f, term = 1.f;
      for (int j = 0; j < 3; ++j) {
        float a = alpha_raw[j];
        float sp = (a > 20.f) ? a : log1pf(__expf(a));
        pf += sp*term; term *= tv;                   // t^0 == 1 even at t=0
      }
      pf *= powf(0.99f, tv);
      ws[WSPF] = pf;
    }
  }
}

// 512 blocks x 512 threads. Block = 8 rows. 8 waves split K (256 each).
// Lane = 16 gate-groups x 4 row-groups; lane tile = 10 gates x 2 rows.
// __launch_bounds__(512,2): 2 blocks/CU -> 128-VGPR cap, no spills (R2 had
// (512,4) -> 64-VGPR cap -> ~470MB scratch traffic).
__global__ __launch_bounds__(512,2) void main_kernel(
    const float* __restrict__ x, const float* __restrict__ loss,
    const float* __restrict__ grad, const float* __restrict__ W_ih2,
    const float* __restrict__ W_out, const float* __restrict__ b_out,
    const float* __restrict__ c1_0, const float* __restrict__ c2_0,
    const float* __restrict__ ws, float* __restrict__ out)
{
  __shared__ float pbuf[8*8*161];      // partial[w][row][pg]
  __shared__ float wih2[1600];
  __shared__ float g1[8][80];
  __shared__ float h1s[8][20], h2s[8][20];
  __shared__ float c10[20], c20[20];
  __shared__ float invX[8], invG[8], lscA[8], axv[8];
  __shared__ unsigned smaxX[8], smaxG[8];

  const int tid  = threadIdx.x;
  const int w    = tid >> 6, lane = tid & 63;
  const int gg   = lane >> 2, rg = lane & 3;
  const int part = gg >> 3;            // 0 = x part, 1 = grad part
  const int ggp  = gg & 7;
  const int r0   = blockIdx.x * 8;

  for (int i = tid; i < 1600; i += 512) wih2[i] = W_ih2[i];
  if (tid < 20) { c10[tid] = c1_0[tid]; c20[tid] = c2_0[tid]; }
  if (tid < 8)  { smaxX[tid] = 0u; smaxG[tid] = 0u; }
  __syncthreads();

  const float* xsrc = part ? grad : x;
  const float* p0 = xsrc + (size_t)(r0 + 2*rg)*2048 + w*256;
  const float* p1 = p0 + 2048;
  const float* pw = ws + (part ? WS2G : WS2X) + (size_t)ggp*20480 + (size_t)(w*64)*160;

  float acc[10][2];
  #pragma unroll
  for (int jj = 0; jj < 10; ++jj) { acc[jj][0] = 0.f; acc[jj][1] = 0.f; }
  float vm0 = 0.f, vm1 = 0.f;

  #pragma unroll 1
  for (int kk = 0; kk < 64; ++kk) {
    const float4 xa = *(const float4*)p0;
    const float4 xb = *(const float4*)p1;
    // batch 1: gates 0..4 (limits live W regs to 5 float4)
    {
      float4 wv[5];
      #pragma unroll
      for (int jj = 0; jj < 5; ++jj) wv[jj] = *(const float4*)(pw + jj*4);
      #pragma unroll
      for (int jj = 0; jj < 5; ++jj) {
        acc[jj][0] = fmaf(wv[jj].x, xa.x, acc[jj][0]);
        acc[jj][0] = fmaf(wv[jj].y, xa.y, acc[jj][0]);
        acc[jj][0] = fmaf(wv[jj].z, xa.z, acc[jj][0]);
        acc[jj][0] = fmaf(wv[jj].w, xa.w, acc[jj][0]);
        acc[jj][1] = fmaf(wv[jj].x, xb.x, acc[jj][1]);
        acc[jj][1] = fmaf(wv[jj].y, xb.y, acc[jj][1]);
        acc[jj][1] = fmaf(wv[jj].z, xb.z, acc[jj][1]);
        acc[jj][1] = fmaf(wv[jj].w, xb.w, acc[jj][1]);
      }
    }
    // batch 2: gates 5..9
    {
      float4 wv[5];
      #pragma unroll
      for (int jj = 0; jj < 5; ++jj) wv[jj] = *(const float4*)(pw + 20 + jj*4);
      #pragma unroll
      for (int jj = 0; jj < 5; ++jj) {
        acc[5+jj][0] = fmaf(wv[jj].x, xa.x, acc[5+jj][0]);
        acc[5+jj][0] = fmaf(wv[jj].y, xa.y, acc[5+jj][0]);
        acc[5+jj][0] = fmaf(wv[jj].z, xa.z, acc[5+jj][0]);
        acc[5+jj][0] = fmaf(wv[jj].w, xa.w, acc[5+jj][0]);
        acc[5+jj][1] = fmaf(wv[jj].x, xb.x, acc[5+jj][1]);
        acc[5+jj][1] = fmaf(wv[jj].y, xb.y, acc[5+jj][1]);
        acc[5+jj][1] = fmaf(wv[jj].z, xb.z, acc[5+jj][1]);
        acc[5+jj][1] = fmaf(wv[jj].w, xb.w, acc[5+jj][1]);
      }
    }
    vm0 = fmaxf(vm0, fmaxf(fmaxf(fabsf(xa.x),fabsf(xa.y)), fmaxf(fabsf(xa.z),fabsf(xa.w))));
    vm1 = fmaxf(vm1, fmaxf(fmaxf(fabsf(xb.x),fabsf(xb.y)), fmaxf(fabsf(xb.z),fabsf(xb.w))));
    p0 += 4; p1 += 4; pw += 160;
  }

  if (ggp == 0) {                      // one lane per (part,row-pair) per wave
    unsigned* dm = part ? smaxG : smaxX;
    atomicMax(&dm[2*rg],   __float_as_uint(vm0));
    atomicMax(&dm[2*rg+1], __float_as_uint(vm1));
  }
  #pragma unroll
  for (int jj = 0; jj < 10; ++jj) {    // pg = gg*10+jj: 0..79 x-part, 80..159 g-part
    pbuf[(w*8 + 2*rg+0)*161 + gg*10+jj] = acc[jj][0];
    pbuf[(w*8 + 2*rg+1)*161 + gg*10+jj] = acc[jj][1];
  }
  __syncthreads();

  if (tid < 8) {
    float ax = __uint_as_float(smaxX[tid]); ax = (ax > 0.f) ? ax : 1.0f;
    axv[tid] = ax; invX[tid] = 1.0f/ax;
    float ag = __uint_as_float(smaxG[tid]); ag = (ag > 0.f) ? ag : 1.0f;
    invG[tid] = 1.0f/ag;
    float l  = loss[r0 + tid];
    float al = fabsf(l); al = (al > 0.f) ? al : 1.0f;
    lscA[tid] = l / al;
  }
  __syncthreads();

  for (int idx = tid; idx < 640; idx += 512) {       // gates 1
    const int r = idx / 80, k2 = idx - r*80;
    float sx = 0.f, sg = 0.f;
    #pragma unroll
    for (int ww = 0; ww < 8; ++ww) {
      sx += pbuf[(ww*8 + r)*161 + k2];
      sg += pbuf[(ww*8 + r)*161 + 80 + k2];
    }
    g1[r][k2] = sx*invX[r] + sg*invG[r] + ws[WSL+k2]*lscA[r] + ws[WSC1+k2];
  }
  __syncthreads();

  if (tid < 160) {                                   // cell 1
    const int r = tid / 20, j = tid - r*20;
    const float gi = g1[r][j], gf = g1[r][20+j], gc = g1[r][40+j], go = g1[r][60+j];
    const float c1 = fsig(gf)*c10[j] + fsig(gi)*ftanh(gc);
    h1s[r][j] = fsig(go)*ftanh(c1);
  }
  __syncthreads();

  for (int idx = tid; idx < 640; idx += 512) {       // gates 2
    const int r = idx / 80, k2 = idx - r*80;
    float s = ws[WSC2+k2];
    #pragma unroll
    for (int j = 0; j < 20; ++j) s += wih2[k2*20+j]*h1s[r][j];
    g1[r][k2] = s;
  }
  __syncthreads();

  if (tid < 160) {                                   // cell 2
    const int r = tid / 20, j = tid - r*20;
    const float gi = g1[r][j], gf = g1[r][20+j], gc = g1[r][40+j], go = g1[r][60+j];
    const float c2v = fsig(gf)*c20[j] + fsig(gi)*ftanh(gc);
    h2s[r][j] = fsig(go)*ftanh(c2v);
  }
  __syncthreads();

  const float pf = ws[WSPF];                         // output GEMV + tanh + scale
  #pragma unroll
  for (int q = 0; q < 4; ++q) {
    const int d = q*512 + tid;
    const float4* wr = (const float4*)(W_out + (size_t)d*20);
    const float4 w0 = wr[0], w1 = wr[1], w2 = wr[2], w3 = wr[3], w4 = wr[4];
    const float bo = b_out[d];
    #pragma unroll
    for (int r = 0; r < 8; ++r) {
      const float4* hp = (const float4*)&h2s[r][0];
      const float4 h0 = hp[0], h1v = hp[1], h2v = hp[2], h3v = hp[3], h4v = hp[4];
      float v = bo;
      v += w0.x*h0.x  + w0.y*h0.y  + w0.z*h0.z  + w0.w*h0.w;
      v += w1.x*h1v.x + w1.y*h1v.y + w1.z*h1v.z + w1.w*h1v.w;
      v += w2.x*h2v.x + w2.y*h2v.y + w2.z*h2v.z + w2.w*h2v.w;
      v += w3.x*h3v.x + w3.y*h3v.y + w3.z*h3v.z + w3.w*h3v.w;
      v += w4.x*h4v.x + w4.y*h4v.y + w4.z*h4v.z + w4.w*h4v.w;
      out[(size_t)(r0+r)*2048 + d] = pf * axv[r] * ftanh(v);
    }
  }
}

extern "C" void kernel_launch(void* const* d_in, const int* in_sizes, int n_in,
                              void* d_out, int out_size, void* d_ws, size_t ws_size,
                              hipStream_t stream)
{
  const float* x      = (const float*)d_in[0];
  const float* loss   = (const float*)d_in[1];
  const float* grad   = (const float*)d_in[2];
  const float* W_ih1  = (const float*)d_in[3];
  const float* b_ih1  = (const float*)d_in[4];
  const float* W_hh1  = (const float*)d_in[5];
  const float* b_hh1  = (const float*)d_in[6];
  const float* W_ih2  = (const float*)d_in[7];
  const float* b_ih2  = (const float*)d_in[8];
  const float* W_hh2  = (const float*)d_in[9];
  const float* b_hh2  = (const float*)d_in[10];
  const float* W_out  = (const float*)d_in[11];
  const float* b_out  = (const float*)d_in[12];
  const float* h1_0   = (const float*)d_in[13];
  const float* c1_0   = (const float*)d_in[14];
  const float* h2_0   = (const float*)d_in[15];
  const float* c2_0   = (const float*)d_in[16];
  const float* alpha  = (const float*)d_in[17];
  const int*   t      = (const int*)d_in[18];
  float* ws  = (float*)d_ws;
  float* out = (float*)d_out;

  hipLaunchKernelGGL(prep_kernel, dim3(160), dim3(256), 0, stream,
                     W_ih1, b_ih1, W_hh1, b_hh1, b_ih2, W_hh2, b_hh2,
                     h1_0, h2_0, alpha, t, ws);
  hipLaunchKernelGGL(main_kernel, dim3(512), dim3(512), 0, stream,
                     x, loss, grad, W_ih2, W_out, b_out, c1_0, c2_0, ws, out);
}